// Round 2
// baseline (1978.632 us; speedup 1.0000x reference)
//
#include <hip/hip_runtime.h>

#define T_STEPS 2048
#define N_BATCH 256
#define RH 47

__device__ __forceinline__ float fast_rcp(float x) { return __builtin_amdgcn_rcpf(x); }

// tanh(c) = 2/(1+e^{-2c}) - 1
__device__ __forceinline__ float tanh_f(float c) {
    float e = __expf(-2.0f * c);
    return fmaf(2.0f, fast_rcp(1.0f + e), -1.0f);
}

__global__ __launch_bounds__(832) void adrnn_fused(
    const float* __restrict__ x_r, const float* __restrict__ x_t,
    const float* __restrict__ rWih0, const float* __restrict__ rWhh0,
    const float* __restrict__ rbih0, const float* __restrict__ rbhh0,
    const float* __restrict__ rWih1, const float* __restrict__ rWhh1,
    const float* __restrict__ rbih1, const float* __restrict__ rbhh1,
    const float* __restrict__ tWih0, const float* __restrict__ tWhh0,
    const float* __restrict__ tbih0, const float* __restrict__ tbhh0,
    const float* __restrict__ tWih1, const float* __restrict__ tWhh1,
    const float* __restrict__ tbih1, const float* __restrict__ tbhh1,
    float* __restrict__ r_out, float* __restrict__ t_out)
{
    // LDS: input vectors + activated gates + cell states + x ring for the t-RNN
    __shared__ __align__(16) float in0[96];   // [x_r(47) | x_t(2) | hr0(47)]
    __shared__ __align__(16) float in1[96];   // [hr0(47) | pad | hr1(47) | pad]
    __shared__ __align__(16) float act0[188];
    __shared__ __align__(16) float act1[188];
    __shared__ float cr0[48];
    __shared__ float cr1[48];
    __shared__ float xcpy[4][49];             // depth-4 ring of x(t) for t-RNN

    const int tid = threadIdx.x;
    const int b = blockIdx.x;
    const size_t xr_base = (size_t)b * T_STEPS * 47;
    const size_t xt_base = (size_t)b * T_STEPS * 2;

    // zero-init states
    if (tid < 47) {
        in0[49 + tid] = 0.0f;
        in1[tid] = 0.0f;
        in1[48 + tid] = 0.0f;
        cr0[tid] = 0.0f;
        cr1[tid] = 0.0f;
    }
    if (tid == 47) { in1[47] = 0.0f; in1[95] = 0.0f; }
    __syncthreads();   // barrier #1 (all waves)

    if (tid < 384) {
        // ================= A group: layer-0 gates, 2 lanes per gate =================
        const int g = tid >> 1, q = tid & 1;
        const bool active = (tid < 376);
        float wA[48];
#pragma unroll
        for (int u = 0; u < 48; ++u) {
            int k = q * 48 + u;               // col: 0..48 = [x_r|x_t], 49..95 = hr0
            float w = 0.0f;
            if (active) w = (k < 49) ? rWih0[g * 49 + k] : rWhh0[g * 47 + (k - 49)];
            wA[u] = w;
        }
        const float bias = active ? (rbih0[g] + rbhh0[g]) : 0.0f;
        const bool isg = (g >= 94 && g < 141);
        const float zm = isg ? 2.0f : 1.0f, sm = isg ? 2.0f : 1.0f, sa = isg ? -1.0f : 0.0f;
        const int j = tid;                    // update lane if < 47
        const int qb = q * 48;

        __syncthreads();                      // barrier #2 (pre-loop)
        for (int i = 0; i <= T_STEPS + 1; ++i) {
            if (i < T_STEPS && active) {
                float a0 = 0.f, a1 = 0.f, a2 = 0.f, a3 = 0.f;
#pragma unroll
                for (int u = 0; u < 48; u += 4) {
                    a0 = fmaf(wA[u + 0], in0[qb + u + 0], a0);
                    a1 = fmaf(wA[u + 1], in0[qb + u + 1], a1);
                    a2 = fmaf(wA[u + 2], in0[qb + u + 2], a2);
                    a3 = fmaf(wA[u + 3], in0[qb + u + 3], a3);
                }
                float acc = (a0 + a1) + (a2 + a3);
                acc += __shfl_xor(acc, 1, 64);
                acc += bias;
                float e = __expf(-acc * zm);
                float s = fast_rcp(1.0f + e);
                float av = fmaf(s, sm, sa);
                if (q == 0) act0[g] = av;
            }
            __syncthreads();  // end P1
            if (i < T_STEPS && j < 47) {
                float iv = act0[j], fv = act0[47 + j], gv = act0[94 + j], ov = act0[141 + j];
                float c = fmaf(fv, cr0[j], iv * gv);
                cr0[j] = c;
                float h = ov * tanh_f(c);
                in0[49 + j] = h;
                in1[j] = h;
            }
            __syncthreads();  // end P2
        }
    } else if (tid < 768) {
        // ================= B group: layer-1 gates (lagging one step) =================
        const int tb = tid - 384;
        const int g = tb >> 1, q = tb & 1;
        const bool active = (tb < 376);
        float wB[48];
#pragma unroll
        for (int u = 0; u < 48; ++u) {
            int k = q * 48 + u;               // padded cols: 0..46 hr0, 47 pad, 48..94 hr1, 95 pad
            float w = 0.0f;
            if (active) {
                if (k < 47) w = rWih1[g * 47 + k];
                else if (k >= 48 && k < 95) w = rWhh1[g * 47 + (k - 48)];
            }
            wB[u] = w;
        }
        const float bias = active ? (rbih1[g] + rbhh1[g]) : 0.0f;
        const bool isg = (g >= 94 && g < 141);
        const float zm = isg ? 2.0f : 1.0f, sm = isg ? 2.0f : 1.0f, sa = isg ? -1.0f : 0.0f;
        const int j = tb;
        const int qb = q * 48;

        __syncthreads();                      // pre-loop
        for (int i = 0; i <= T_STEPS + 1; ++i) {
            if (i >= 1 && i <= T_STEPS && active) {
                float a0 = 0.f, a1 = 0.f, a2 = 0.f, a3 = 0.f;
#pragma unroll
                for (int u = 0; u < 48; u += 4) {
                    a0 = fmaf(wB[u + 0], in1[qb + u + 0], a0);
                    a1 = fmaf(wB[u + 1], in1[qb + u + 1], a1);
                    a2 = fmaf(wB[u + 2], in1[qb + u + 2], a2);
                    a3 = fmaf(wB[u + 3], in1[qb + u + 3], a3);
                }
                float acc = (a0 + a1) + (a2 + a3);
                acc += __shfl_xor(acc, 1, 64);
                acc += bias;
                float e = __expf(-acc * zm);
                float s = fast_rcp(1.0f + e);
                float av = fmaf(s, sm, sa);
                if (q == 0) act1[g] = av;
            }
            __syncthreads();  // end P1
            if (i >= 1 && i <= T_STEPS && j < 47) {
                float iv = act1[j], fv = act1[47 + j], gv = act1[94 + j], ov = act1[141 + j];
                float c = fmaf(fv, cr1[j], iv * gv);
                cr1[j] = c;
                float h = ov * tanh_f(c);
                in1[48 + j] = h;
                r_out[((size_t)b * T_STEPS + (i - 1)) * 47 + j] = h;
            }
            __syncthreads();  // end P2
        }
    } else {
        // ================= T wave: t-RNN (lagging TWO steps) + x staging =================
        const int l = tid - 768;
        const int gt = l >> 3, p = l & 7;     // t0: 8 lanes per gate
        float wT[12];
#pragma unroll
        for (int u = 0; u < 12; ++u) wT[u] = tWih0[gt * 96 + p * 12 + u];
        const float bT0 = tbih0[gt] + tbhh0[gt];
        const float wh00 = tWhh0[gt * 2 + 0], wh01 = tWhh0[gt * 2 + 1];
        const int g1 = l & 7;                 // t1: 1 lane per gate (replicated x8)
        const float wi10 = tWih1[g1 * 2 + 0], wi11 = tWih1[g1 * 2 + 1];
        const float wh10 = tWhh1[g1 * 2 + 0], wh11 = tWhh1[g1 * 2 + 1];
        const float bT1 = tbih1[g1] + tbhh1[g1];
        const bool isg0 = ((gt >> 1) == 2);
        const float zm0 = isg0 ? 2.f : 1.f, sm0 = isg0 ? 2.f : 1.f, sa0 = isg0 ? -1.f : 0.f;
        const bool isg1 = ((g1 >> 1) == 2);
        const float zm1 = isg1 ? 2.f : 1.f, sm1 = isg1 ? 2.f : 1.f, sa1 = isg1 ? -1.f : 0.f;
        float ht00 = 0.f, ht01 = 0.f, ct00 = 0.f, ct01 = 0.f;
        float ht10 = 0.f, ht11 = 0.f, ct10 = 0.f, ct11 = 0.f;

        float xv[4] = {0.f, 0.f, 0.f, 0.f};
        // prologue: x(0) -> in0 & xcpy[0]; then issue x(1) into regs
        if (l < 16) {
#pragma unroll
            for (int u = 0; u < 4; ++u) {
                int v = l + 16 * u;
                if (v < 47) xv[u] = x_r[xr_base + v];
                else if (v < 49) xv[u] = x_t[xt_base + (v - 47)];
            }
#pragma unroll
            for (int u = 0; u < 4; ++u) {
                int v = l + 16 * u;
                if (v < 49) { in0[v] = xv[u]; xcpy[0][v] = xv[u]; }
            }
#pragma unroll
            for (int u = 0; u < 4; ++u) {
                int v = l + 16 * u;
                if (v < 47) xv[u] = x_r[xr_base + 47 + v];
                else if (v < 49) xv[u] = x_t[xt_base + 2 + (v - 47)];
            }
        }
        __syncthreads();                      // pre-loop (pairs with A/B pre-loop)

        float act0t = 0.0f;
        for (int i = 0; i <= T_STEPS + 1; ++i) {
            if (i >= 2) {
                // t0 gates for step tau = i-2; input = [x(tau)(49) | hr1(tau)(47)]
                // hr1(tau) was written by B at iteration (tau+1 = i-1)'s P2 -> visible here.
                const float* xc = xcpy[(i - 2) & 3];
                float a0 = 0.f, a1 = 0.f, a2 = 0.f, a3 = 0.f;
#pragma unroll
                for (int u = 0; u < 12; u += 4) {
#pragma unroll
                    for (int s2 = 0; s2 < 4; ++s2) {
                        int idx = p * 12 + u + s2;
                        const float* src = (idx < 49) ? (xc + idx) : (in1 + idx - 1);
                        float v = *src;
                        if (s2 == 0) a0 = fmaf(wT[u + 0], v, a0);
                        else if (s2 == 1) a1 = fmaf(wT[u + 1], v, a1);
                        else if (s2 == 2) a2 = fmaf(wT[u + 2], v, a2);
                        else a3 = fmaf(wT[u + 3], v, a3);
                    }
                }
                float acc = (a0 + a1) + (a2 + a3);
                acc += __shfl_xor(acc, 1, 64);
                acc += __shfl_xor(acc, 2, 64);
                acc += __shfl_xor(acc, 4, 64);
                float pre = acc + bT0 + wh00 * ht00 + wh01 * ht01;
                float e = __expf(-pre * zm0);
                float s = fast_rcp(1.0f + e);
                act0t = fmaf(s, sm0, sa0);
            }
            __syncthreads();  // end P1
            if (i >= 2) {
                float iv0 = __shfl(act0t, 0, 64), iv1 = __shfl(act0t, 8, 64);
                float fv0 = __shfl(act0t, 16, 64), fv1 = __shfl(act0t, 24, 64);
                float gv0 = __shfl(act0t, 32, 64), gv1 = __shfl(act0t, 40, 64);
                float ov0 = __shfl(act0t, 48, 64), ov1 = __shfl(act0t, 56, 64);
                ct00 = fmaf(fv0, ct00, iv0 * gv0);
                ct01 = fmaf(fv1, ct01, iv1 * gv1);
                ht00 = ov0 * tanh_f(ct00);
                ht01 = ov1 * tanh_f(ct01);
                float pre1 = bT1 + wi10 * ht00 + wi11 * ht01 + wh10 * ht10 + wh11 * ht11;
                float e1 = __expf(-pre1 * zm1);
                float s1 = fast_rcp(1.0f + e1);
                float a1v = fmaf(s1, sm1, sa1);
                float ji0 = __shfl(a1v, 0, 64), ji1 = __shfl(a1v, 1, 64);
                float jf0 = __shfl(a1v, 2, 64), jf1 = __shfl(a1v, 3, 64);
                float jg0 = __shfl(a1v, 4, 64), jg1 = __shfl(a1v, 5, 64);
                float jo0 = __shfl(a1v, 6, 64), jo1 = __shfl(a1v, 7, 64);
                ct10 = fmaf(jf0, ct10, ji0 * jg0);
                ct11 = fmaf(jf1, ct11, ji1 * jg1);
                ht10 = jo0 * tanh_f(ct10);
                ht11 = jo1 * tanh_f(ct11);
                if (l < 2) t_out[((size_t)b * T_STEPS + (i - 2)) * 2 + l] = (l == 0) ? ht10 : ht11;
            }
            // staging: publish x(i+1) (held in regs) then issue loads for x(i+2)
            if (l < 16) {
                const int tw = i + 1;
                if (tw < T_STEPS) {
#pragma unroll
                    for (int u = 0; u < 4; ++u) {
                        int v = l + 16 * u;
                        if (v < 49) { in0[v] = xv[u]; xcpy[tw & 3][v] = xv[u]; }
                    }
                }
                int tl = i + 2; if (tl > T_STEPS - 1) tl = T_STEPS - 1;
                const size_t xrb = xr_base + (size_t)tl * 47;
                const size_t xtb = xt_base + (size_t)tl * 2;
#pragma unroll
                for (int u = 0; u < 4; ++u) {
                    int v = l + 16 * u;
                    if (v < 47) xv[u] = x_r[xrb + v];
                    else if (v < 49) xv[u] = x_t[xtb + (v - 47)];
                }
            }
            __syncthreads();  // end P2
        }
    }
}

extern "C" void kernel_launch(void* const* d_in, const int* in_sizes, int n_in,
                              void* d_out, int out_size, void* d_ws, size_t ws_size,
                              hipStream_t stream) {
    const float* x_r   = (const float*)d_in[0];
    const float* x_t   = (const float*)d_in[1];
    const float* rWih0 = (const float*)d_in[2];
    const float* rWhh0 = (const float*)d_in[3];
    const float* rbih0 = (const float*)d_in[4];
    const float* rbhh0 = (const float*)d_in[5];
    const float* rWih1 = (const float*)d_in[6];
    const float* rWhh1 = (const float*)d_in[7];
    const float* rbih1 = (const float*)d_in[8];
    const float* rbhh1 = (const float*)d_in[9];
    const float* tWih0 = (const float*)d_in[10];
    const float* tWhh0 = (const float*)d_in[11];
    const float* tbih0 = (const float*)d_in[12];
    const float* tbhh0 = (const float*)d_in[13];
    const float* tWih1 = (const float*)d_in[14];
    const float* tWhh1 = (const float*)d_in[15];
    const float* tbih1 = (const float*)d_in[16];
    const float* tbhh1 = (const float*)d_in[17];

    float* r_out = (float*)d_out;
    float* t_out = r_out + (size_t)N_BATCH * T_STEPS * 47;

    hipLaunchKernelGGL(adrnn_fused, dim3(N_BATCH), dim3(832), 0, stream,
                       x_r, x_t, rWih0, rWhh0, rbih0, rbhh0, rWih1, rWhh1, rbih1, rbhh1,
                       tWih0, tWhh0, tbih0, tbhh0, tWih1, tWhh1, tbih1, tbhh1,
                       r_out, t_out);
}